// Round 10
// baseline (407.709 us; speedup 1.0000x reference)
//
#include <hip/hip_runtime.h>
#include <math.h>

#define BB 32
#define CCH 224
#define TTT 2048
#define TPB 128            // t per tile in kf
#define NT  (TTT/TPB)      // 16 global tiles
#define CG  28             // chains (channels) per kf block (halo-optimal)
#define NCG (CCH/CG)       // 8
#define IROW 29            // f64 per I row (28 + 1 pad)
#define CPW 4              // channels per conv thread (7 conv waves)

// LDS-only barrier: cross-wave deps in kf are all through LDS (Is, bitsb).
// Stores stay fire-and-forget; prefetch loads stay in flight across barriers.
__device__ __forceinline__ void bar_lds() {
    asm volatile("s_waitcnt lgkmcnt(0)" ::: "memory");
    __builtin_amdgcn_s_barrier();
    asm volatile("" ::: "memory");
}

// ---------------------------------------------------------------------------
// kw v3: per (b,t): f64 dot over C -> w -> 7 symmetric Gaussian taps (f64).
// 1024-thread blocks: 256 t x 4 channel-quarters; grid (8,32).
// Summation order preserved exactly: p_q sequential, (p0+p1)+(p2+p3).
// ---------------------------------------------------------------------------
__global__ __launch_bounds__(1024) void kw(
    const float* __restrict__ x, const float* __restrict__ lw,
    double* __restrict__ kernG)
{
    __shared__ double sp[4][256];
    const int b  = blockIdx.y;
    const int tl = threadIdx.x & 255;          // t within block tile
    const int q  = threadIdx.x >> 8;           // channel quarter 0..3
    const int t  = blockIdx.x * 256 + tl;

    const float* xb  = x + (((size_t)(b * CCH + 56 * q)) << 11) + t;
    const float* lwq = lw + 56 * q;

    double p = 0.0;
    #pragma unroll 8
    for (int i = 0; i < 56; ++i)
        p += (double)xb[(size_t)i << 11] * (double)lwq[i];
    sp[q][tl] = p;
    __syncthreads();

    if (threadIdx.x < 256) {
        const int tt = blockIdx.x * 256 + threadIdx.x;
        double acc = (sp[0][threadIdx.x] + sp[1][threadIdx.x])
                   + (sp[2][threadIdx.x] + sp[3][threadIdx.x]);

        double w = 5.2 + acc * 9.6;
        w = fmin(fmax(w, 0.4), 10.0);
        double iw2 = 1.0 / (w * w);

        // norm over linspace(-60,60,130): symmetric -> 2x half-sum,
        // terms G^{(2u+1)^2} via power recurrence (2 exps total)
        const double s = 120.0 / 129.0;
        double G  = exp(-0.125 * s * s * iw2);
        double G2 = G * G, G4 = G2 * G2, G8 = G4 * G4;
        double term = G, cmul = G8, norm = G;
        for (int u = 1; u <= 64; ++u) { term *= cmul; cmul *= G8; norm += term; }
        norm *= 2.0;

        double P = exp(-0.5 * iw2), P2 = P * P;
        double a = 1.0, bm = P, inv = 1.0 / norm;
        double* kr = kernG + (size_t)(b * TTT + tt) * 7;
        kr[0] = inv;                      // center tap
        #pragma unroll
        for (int d = 1; d <= 6; ++d) {
            a *= bm; bm *= P2;
            kr[d] = a * inv;              // tap at distance d (symmetric)
        }
    }
}

// ---------------------------------------------------------------------------
// kf v10: fused conv + LIF scan + spikes, SEGMENTED over t.
// grid (8, 32, 2) x 512 threads = 2 blocks/CU (LDS 59.4KB x2 = 119KB;
// __launch_bounds__(512,4) pins VGPR<=128 so both blocks fit).
// Segment 0: tiles 0..9, exact (mem starts 0 = true init).
// Segment 1: warmup tiles 5..9 from guess mem=0 (outputs discarded), then
//   output tiles 10..15. Warmup = 640 steps: state error decays x0.95/step
//   -> residual ~1e-15; transient decision flips self-heal (any flip >224
//   steps before output decays below the f32-class scale that r9 proved
//   flip-free across 134M decisions).
// Everything else is byte-identical to the verified r5/v6 kernel:
// reg-held x (2-phase prefetch), f64 Is double-buffer, f64 scan with the
// r5 step idiom (fastest measured: 58cyc/step), 1 barrier per phase.
// ---------------------------------------------------------------------------
__global__ __launch_bounds__(512, 4) void kf(
    const float* __restrict__ x, const double* __restrict__ kernG,
    float* __restrict__ out)
{
    __shared__ double Is[2][TPB][IROW];                // 59392 B
    __shared__ unsigned long long bitsb[2][CG][2];     //   896 B

    const int b   = blockIdx.y;
    const int cgi = blockIdx.x;
    const int seg = blockIdx.z;
    const int c0  = cgi * CG;
    const int tid = threadIdx.x;
    const int ctid = tid - 64;          // 0..447 for conv waves

    const int T0   = seg ? 5  : 0;      // global tile of local tile 0
    const int NTL  = seg ? 11 : 10;     // local tiles this block processes
    const int OUT0 = seg ? 5  : 0;      // first OUTPUT local tile

    const float*  xbase = x + (((size_t)(b * CCH)) << 11);
    const double* kbase = kernG + (size_t)(b * TTT) * 7;
    float* obase = out + (((size_t)(b * CCH + c0)) << 11);

    double mem = 0.0;   // scan state; =0 is exact init (seg0) / guess (seg1)
    bool   r   = false;

    const int tl = ctid & 63;           // conv lane t within half
    const int g  = ctid >> 6;           // conv wave group 0..6
    const int cb = CPW * g;             // first channel (relative) of group

    // issue all global loads for one LOCAL tile into a reg set (conv waves)
    auto issue = [&](int tile, float (&rv)[2][16], double (&kv)[2][7]) {
        const int gt0 = (T0 + tile) * TPB;
        #pragma unroll
        for (int h = 0; h < 2; ++h) {
            const int tt = gt0 + tl + 64 * h;
            #pragma unroll
            for (int i = 0; i < 16; ++i) {
                int cr = c0 + cb - 6 + i;
                rv[h][i] = (cr >= 0 && cr < CCH)
                         ? xbase[((size_t)cr << 11) + tt] : 0.f;
            }
            const double* kp = kbase + (size_t)tt * 7;
            #pragma unroll
            for (int i = 0; i < 7; ++i) kv[h][i] = kp[i];
        }
    };

    auto phase = [&](int k, float (&rv)[2][16], double (&kv)[2][7]) {
        if (tid >= 64) {
            const int buf = k & 1;
            // (1) out-write(k-2): fire-and-forget coalesced float4 stores
            //     (skipped for warmup tiles)
            if (k >= 2 && k - 2 >= OUT0) {
                const int j = k - 2, jb = j & 1;
                const int t0o = (T0 + j) * TPB;
                const int c = ctid >> 4, q = ctid & 15;
                #pragma unroll
                for (int h = 0; h < 2; ++h) {
                    unsigned long long bits = bitsb[jb][c][h] >> (4 * q);
                    float4 v;
                    v.x = (bits & 1ull) ? 1.0f : 0.0f;
                    v.y = (bits & 2ull) ? 1.0f : 0.0f;
                    v.z = (bits & 4ull) ? 1.0f : 0.0f;
                    v.w = (bits & 8ull) ? 1.0f : 0.0f;
                    *(float4*)(obase + ((size_t)c << 11) + t0o + 64 * h + 4 * q) = v;
                }
            }
            // (2) conv(k): registers -> Is[buf]; two t-halves sequentially
            if (k <= NTL - 1) {
                #pragma unroll
                for (int h = 0; h < 2; ++h) {
                    double kk7[7];
                    #pragma unroll
                    for (int i = 0; i < 7; ++i) kk7[i] = kv[h][i];
                    double xv[16];
                    #pragma unroll
                    for (int i = 0; i < 16; ++i) xv[i] = (double)rv[h][i];
                    #pragma unroll
                    for (int c = 0; c < CPW; ++c) {
                        double acc = 0.0;
                        #pragma unroll
                        for (int kk = 0; kk < 13; ++kk) {
                            int d = kk < 6 ? 6 - kk : kk - 6;
                            acc = fma(xv[c + kk], kk7[d], acc);
                        }
                        double xvv = xv[c + 6];
                        double dd  = xvv - acc;
                        Is[buf][tl + 64 * h][cb + c] = xvv - (dd > 0.0 ? dd : 0.0);
                    }
                }
            }
            // (3) issue loads for local tile k+2
            if (k + 2 <= NTL - 1) issue(k + 2, rv, kv);
        } else {
            // scan(k-1): 128 f64 LIF steps, r5-verified step form, 8-deep
            // double-buffered prefetch
            if (k >= 1 && k <= NTL) {
                const int p = (k - 1) & 1;
                const int c = tid;
                __builtin_amdgcn_s_setprio(1);
                if (c < CG) {
                    unsigned long long bits0 = 0ull, bits1 = 0ull;
                    double va[8], vb8[8], ca[8], cb2[8];
                    #pragma unroll
                    for (int j2 = 0; j2 < 8; ++j2) va[j2] = Is[p][j2][c];
                    #pragma unroll
                    for (int j2 = 0; j2 < 8; ++j2) ca[j2] = va[j2] - 1.0;
                    for (int g2 = 0; g2 < TPB; g2 += 16) {
                        #pragma unroll
                        for (int j2 = 0; j2 < 8; ++j2) vb8[j2] = Is[p][g2 + 8 + j2][c];
                        #pragma unroll
                        for (int j2 = 0; j2 < 8; ++j2) cb2[j2] = vb8[j2] - 1.0;
                        #pragma unroll
                        for (int j2 = 0; j2 < 8; ++j2) {
                            double m1 = fma(0.95, mem, va[j2]);
                            double m2 = fma(0.95, mem, ca[j2]);
                            mem = r ? m2 : m1;
                            r = mem > 1.0;
                            const int s = g2 + j2;
                            unsigned long long bbit =
                                (unsigned long long)(r ? 1 : 0) << (s & 63);
                            if (s < 64) bits0 |= bbit; else bits1 |= bbit;
                        }
                        if (g2 + 16 < TPB) {
                            #pragma unroll
                            for (int j2 = 0; j2 < 8; ++j2) va[j2] = Is[p][g2 + 16 + j2][c];
                            #pragma unroll
                            for (int j2 = 0; j2 < 8; ++j2) ca[j2] = va[j2] - 1.0;
                        }
                        #pragma unroll
                        for (int j2 = 0; j2 < 8; ++j2) {
                            double m1 = fma(0.95, mem, vb8[j2]);
                            double m2 = fma(0.95, mem, cb2[j2]);
                            mem = r ? m2 : m1;
                            r = mem > 1.0;
                            const int s = g2 + 8 + j2;
                            unsigned long long bbit =
                                (unsigned long long)(r ? 1 : 0) << (s & 63);
                            if (s < 64) bits0 |= bbit; else bits1 |= bbit;
                        }
                    }
                    bitsb[p][c][0] = bits0;
                    bitsb[p][c][1] = bits1;
                }
                __builtin_amdgcn_s_setprio(0);
            }
        }
        bar_lds();
    };

    // ping-pong register sets (statically indexed — rule #20)
    float  rA[2][16], rB[2][16];
    double kA[2][7],  kB[2][7];

    // prologue: issue local tiles 0 (set A) and 1 (set B)
    if (tid >= 64) {
        issue(0, rA, kA);
        issue(1, rB, kB);
    }

    // NTL+2 phases, unrolled by 2 so reg-set parity is static; tail phase
    // guarded (block-uniform -> barrier-safe)
    for (int kk = 0; kk <= NTL + 1; kk += 2) {
        phase(kk, rA, kA);
        if (kk + 1 <= NTL + 1) phase(kk + 1, rB, kB);
    }
}

// ---------------------------------------------------------------------------
extern "C" void kernel_launch(void* const* d_in, const int* in_sizes, int n_in,
                              void* d_out, int out_size, void* d_ws, size_t ws_size,
                              hipStream_t stream)
{
    const float* x  = (const float*)d_in[0];   // (32,1,224,2048) f32
    const float* lw = (const float*)d_in[1];   // (1,224) f32
    float* out = (float*)d_out;                // (32,1,224,2048) f32

    double* kernG = (double*)d_ws;             // 65536 * 7 * 8 = 3,670,016 B

    kw<<<dim3(TTT / 256, BB), 1024, 0, stream>>>(x, lw, kernG);
    kf<<<dim3(NCG, BB, 2), 512, 0, stream>>>(x, kernG, out);
}

// Round 11
// 214.698 us; speedup vs baseline: 1.8990x; 1.8990x over previous
//
#include <hip/hip_runtime.h>
#include <math.h>

#define BB 32
#define CCH 224
#define TTT 2048
#define TPB 128            // t per tile in kf
#define NT  (TTT/TPB)      // 16 global tiles
#define CG  28             // chains (channels) per kf block (halo-optimal)
#define NCG (CCH/CG)       // 8
#define IROW 29            // f64 per I row (28 + 1 pad)
#define CPW 4              // channels per conv thread (7 conv waves)

// LDS-only barrier: cross-wave deps in kf are all through LDS (Is, bitsb).
// Stores stay fire-and-forget; prefetch loads stay in flight across barriers.
__device__ __forceinline__ void bar_lds() {
    asm volatile("s_waitcnt lgkmcnt(0)" ::: "memory");
    __builtin_amdgcn_s_barrier();
    asm volatile("" ::: "memory");
}

// ---------------------------------------------------------------------------
// kw v3: per (b,t): f64 dot over C -> w -> 7 symmetric Gaussian taps (f64).
// 1024-thread blocks: 256 t x 4 channel-quarters; grid (8,32).
// Summation order preserved exactly: p_q sequential, (p0+p1)+(p2+p3).
// ---------------------------------------------------------------------------
__global__ __launch_bounds__(1024) void kw(
    const float* __restrict__ x, const float* __restrict__ lw,
    double* __restrict__ kernG)
{
    __shared__ double sp[4][256];
    const int b  = blockIdx.y;
    const int tl = threadIdx.x & 255;          // t within block tile
    const int q  = threadIdx.x >> 8;           // channel quarter 0..3
    const int t  = blockIdx.x * 256 + tl;

    const float* xb  = x + (((size_t)(b * CCH + 56 * q)) << 11) + t;
    const float* lwq = lw + 56 * q;

    double p = 0.0;
    #pragma unroll 8
    for (int i = 0; i < 56; ++i)
        p += (double)xb[(size_t)i << 11] * (double)lwq[i];
    sp[q][tl] = p;
    __syncthreads();

    if (threadIdx.x < 256) {
        const int tt = blockIdx.x * 256 + threadIdx.x;
        double acc = (sp[0][threadIdx.x] + sp[1][threadIdx.x])
                   + (sp[2][threadIdx.x] + sp[3][threadIdx.x]);

        double w = 5.2 + acc * 9.6;
        w = fmin(fmax(w, 0.4), 10.0);
        double iw2 = 1.0 / (w * w);

        // norm over linspace(-60,60,130): symmetric -> 2x half-sum,
        // terms G^{(2u+1)^2} via power recurrence (2 exps total)
        const double s = 120.0 / 129.0;
        double G  = exp(-0.125 * s * s * iw2);
        double G2 = G * G, G4 = G2 * G2, G8 = G4 * G4;
        double term = G, cmul = G8, norm = G;
        for (int u = 1; u <= 64; ++u) { term *= cmul; cmul *= G8; norm += term; }
        norm *= 2.0;

        double P = exp(-0.5 * iw2), P2 = P * P;
        double a = 1.0, bm = P, inv = 1.0 / norm;
        double* kr = kernG + (size_t)(b * TTT + tt) * 7;
        kr[0] = inv;                      // center tap
        #pragma unroll
        for (int d = 1; d <= 6; ++d) {
            a *= bm; bm *= P2;
            kr[d] = a * inv;              // tap at distance d (symmetric)
        }
    }
}

// ---------------------------------------------------------------------------
// kf v11: fused conv + LIF scan + spikes, SEGMENTED over t.
// grid (8, 32, 2) x 512 threads; target 2 blocks/CU (LDS 59.4KB x2 = 119KB).
// __launch_bounds__(512, 2): r10 proved the 2nd arg acts as BLOCKS/CU on
// this toolchain (arg=4 forced VGPR=64 -> 600MB scratch spill). arg=2 caps
// VGPR at 128 = r5's natural spill-free allocation, and licenses exactly
// the 2-block co-residency the segmentation needs.
// Segment 0: tiles 0..9, exact (mem starts 0 = true init).
// Segment 1: warmup tiles 5..9 from guess mem=0 (outputs discarded), then
//   output tiles 10..15. Warmup = 640 steps: error decays x0.95/step ->
//   ~1e-15 residual; r10 measured absmax 0.0 -> mechanism validated.
// Everything else byte-identical to the verified r5/v6 kernel.
// ---------------------------------------------------------------------------
__global__ __launch_bounds__(512, 2) void kf(
    const float* __restrict__ x, const double* __restrict__ kernG,
    float* __restrict__ out)
{
    __shared__ double Is[2][TPB][IROW];                // 59392 B
    __shared__ unsigned long long bitsb[2][CG][2];     //   896 B

    const int b   = blockIdx.y;
    const int cgi = blockIdx.x;
    const int seg = blockIdx.z;
    const int c0  = cgi * CG;
    const int tid = threadIdx.x;
    const int ctid = tid - 64;          // 0..447 for conv waves

    const int T0   = seg ? 5  : 0;      // global tile of local tile 0
    const int NTL  = seg ? 11 : 10;     // local tiles this block processes
    const int OUT0 = seg ? 5  : 0;      // first OUTPUT local tile

    const float*  xbase = x + (((size_t)(b * CCH)) << 11);
    const double* kbase = kernG + (size_t)(b * TTT) * 7;
    float* obase = out + (((size_t)(b * CCH + c0)) << 11);

    double mem = 0.0;   // scan state; =0 is exact init (seg0) / guess (seg1)
    bool   r   = false;

    const int tl = ctid & 63;           // conv lane t within half
    const int g  = ctid >> 6;           // conv wave group 0..6
    const int cb = CPW * g;             // first channel (relative) of group

    // issue all global loads for one LOCAL tile into a reg set (conv waves)
    auto issue = [&](int tile, float (&rv)[2][16], double (&kv)[2][7]) {
        const int gt0 = (T0 + tile) * TPB;
        #pragma unroll
        for (int h = 0; h < 2; ++h) {
            const int tt = gt0 + tl + 64 * h;
            #pragma unroll
            for (int i = 0; i < 16; ++i) {
                int cr = c0 + cb - 6 + i;
                rv[h][i] = (cr >= 0 && cr < CCH)
                         ? xbase[((size_t)cr << 11) + tt] : 0.f;
            }
            const double* kp = kbase + (size_t)tt * 7;
            #pragma unroll
            for (int i = 0; i < 7; ++i) kv[h][i] = kp[i];
        }
    };

    auto phase = [&](int k, float (&rv)[2][16], double (&kv)[2][7]) {
        if (tid >= 64) {
            const int buf = k & 1;
            // (1) out-write(k-2): fire-and-forget coalesced float4 stores
            //     (skipped for warmup tiles)
            if (k >= 2 && k - 2 >= OUT0) {
                const int j = k - 2, jb = j & 1;
                const int t0o = (T0 + j) * TPB;
                const int c = ctid >> 4, q = ctid & 15;
                #pragma unroll
                for (int h = 0; h < 2; ++h) {
                    unsigned long long bits = bitsb[jb][c][h] >> (4 * q);
                    float4 v;
                    v.x = (bits & 1ull) ? 1.0f : 0.0f;
                    v.y = (bits & 2ull) ? 1.0f : 0.0f;
                    v.z = (bits & 4ull) ? 1.0f : 0.0f;
                    v.w = (bits & 8ull) ? 1.0f : 0.0f;
                    *(float4*)(obase + ((size_t)c << 11) + t0o + 64 * h + 4 * q) = v;
                }
            }
            // (2) conv(k): registers -> Is[buf]; two t-halves sequentially
            if (k <= NTL - 1) {
                #pragma unroll
                for (int h = 0; h < 2; ++h) {
                    double kk7[7];
                    #pragma unroll
                    for (int i = 0; i < 7; ++i) kk7[i] = kv[h][i];
                    double xv[16];
                    #pragma unroll
                    for (int i = 0; i < 16; ++i) xv[i] = (double)rv[h][i];
                    #pragma unroll
                    for (int c = 0; c < CPW; ++c) {
                        double acc = 0.0;
                        #pragma unroll
                        for (int kk = 0; kk < 13; ++kk) {
                            int d = kk < 6 ? 6 - kk : kk - 6;
                            acc = fma(xv[c + kk], kk7[d], acc);
                        }
                        double xvv = xv[c + 6];
                        double dd  = xvv - acc;
                        Is[buf][tl + 64 * h][cb + c] = xvv - (dd > 0.0 ? dd : 0.0);
                    }
                }
            }
            // (3) issue loads for local tile k+2
            if (k + 2 <= NTL - 1) issue(k + 2, rv, kv);
        } else {
            // scan(k-1): 128 f64 LIF steps, r5-verified step form, 8-deep
            // double-buffered prefetch
            if (k >= 1 && k <= NTL) {
                const int p = (k - 1) & 1;
                const int c = tid;
                __builtin_amdgcn_s_setprio(1);
                if (c < CG) {
                    unsigned long long bits0 = 0ull, bits1 = 0ull;
                    double va[8], vb8[8], ca[8], cb2[8];
                    #pragma unroll
                    for (int j2 = 0; j2 < 8; ++j2) va[j2] = Is[p][j2][c];
                    #pragma unroll
                    for (int j2 = 0; j2 < 8; ++j2) ca[j2] = va[j2] - 1.0;
                    for (int g2 = 0; g2 < TPB; g2 += 16) {
                        #pragma unroll
                        for (int j2 = 0; j2 < 8; ++j2) vb8[j2] = Is[p][g2 + 8 + j2][c];
                        #pragma unroll
                        for (int j2 = 0; j2 < 8; ++j2) cb2[j2] = vb8[j2] - 1.0;
                        #pragma unroll
                        for (int j2 = 0; j2 < 8; ++j2) {
                            double m1 = fma(0.95, mem, va[j2]);
                            double m2 = fma(0.95, mem, ca[j2]);
                            mem = r ? m2 : m1;
                            r = mem > 1.0;
                            const int s = g2 + j2;
                            unsigned long long bbit =
                                (unsigned long long)(r ? 1 : 0) << (s & 63);
                            if (s < 64) bits0 |= bbit; else bits1 |= bbit;
                        }
                        if (g2 + 16 < TPB) {
                            #pragma unroll
                            for (int j2 = 0; j2 < 8; ++j2) va[j2] = Is[p][g2 + 16 + j2][c];
                            #pragma unroll
                            for (int j2 = 0; j2 < 8; ++j2) ca[j2] = va[j2] - 1.0;
                        }
                        #pragma unroll
                        for (int j2 = 0; j2 < 8; ++j2) {
                            double m1 = fma(0.95, mem, vb8[j2]);
                            double m2 = fma(0.95, mem, cb2[j2]);
                            mem = r ? m2 : m1;
                            r = mem > 1.0;
                            const int s = g2 + 8 + j2;
                            unsigned long long bbit =
                                (unsigned long long)(r ? 1 : 0) << (s & 63);
                            if (s < 64) bits0 |= bbit; else bits1 |= bbit;
                        }
                    }
                    bitsb[p][c][0] = bits0;
                    bitsb[p][c][1] = bits1;
                }
                __builtin_amdgcn_s_setprio(0);
            }
        }
        bar_lds();
    };

    // ping-pong register sets (statically indexed — rule #20)
    float  rA[2][16], rB[2][16];
    double kA[2][7],  kB[2][7];

    // prologue: issue local tiles 0 (set A) and 1 (set B)
    if (tid >= 64) {
        issue(0, rA, kA);
        issue(1, rB, kB);
    }

    // NTL+2 phases, unrolled by 2 so reg-set parity is static; tail phase
    // guarded (block-uniform -> barrier-safe)
    for (int kk = 0; kk <= NTL + 1; kk += 2) {
        phase(kk, rA, kA);
        if (kk + 1 <= NTL + 1) phase(kk + 1, rB, kB);
    }
}

// ---------------------------------------------------------------------------
extern "C" void kernel_launch(void* const* d_in, const int* in_sizes, int n_in,
                              void* d_out, int out_size, void* d_ws, size_t ws_size,
                              hipStream_t stream)
{
    const float* x  = (const float*)d_in[0];   // (32,1,224,2048) f32
    const float* lw = (const float*)d_in[1];   // (1,224) f32
    float* out = (float*)d_out;                // (32,1,224,2048) f32

    double* kernG = (double*)d_ws;             // 65536 * 7 * 8 = 3,670,016 B

    kw<<<dim3(TTT / 256, BB), 1024, 0, stream>>>(x, lw, kernG);
    kf<<<dim3(NCG, BB, 2), 512, 0, stream>>>(x, kernG, out);
}

// Round 12
// 171.681 us; speedup vs baseline: 2.3748x; 1.2506x over previous
//
#include <hip/hip_runtime.h>
#include <math.h>

#define BB 32
#define CCH 224
#define TTT 2048
#define TPB 128            // t per tile in kf
#define NT  (TTT/TPB)      // 16 global tiles
#define CG  28             // chains (channels) per kf block (halo-optimal)
#define NCG (CCH/CG)       // 8
#define IROW 29            // f32 per I row (28 + 1 pad)
#define CPW 4              // channels per conv thread (7 conv waves)
#define NSLOT 7            // Is ring depth (lifetime 6 phases -> 7 slots)

// LDS-only barrier: cross-wave deps in kf are all through LDS (IsR, bitsb).
// Stores stay fire-and-forget; prefetch loads stay in flight across barriers.
__device__ __forceinline__ void bar_lds() {
    asm volatile("s_waitcnt lgkmcnt(0)" ::: "memory");
    __builtin_amdgcn_s_barrier();
    asm volatile("" ::: "memory");
}

// ---------------------------------------------------------------------------
// kw v3: per (b,t): f64 dot over C -> w -> 7 symmetric Gaussian taps (f64).
// 1024-thread blocks: 256 t x 4 channel-quarters; grid (8,32).
// Summation order preserved exactly: p_q sequential, (p0+p1)+(p2+p3).
// ---------------------------------------------------------------------------
__global__ __launch_bounds__(1024) void kw(
    const float* __restrict__ x, const float* __restrict__ lw,
    double* __restrict__ kernG)
{
    __shared__ double sp[4][256];
    const int b  = blockIdx.y;
    const int tl = threadIdx.x & 255;          // t within block tile
    const int q  = threadIdx.x >> 8;           // channel quarter 0..3
    const int t  = blockIdx.x * 256 + tl;

    const float* xb  = x + (((size_t)(b * CCH + 56 * q)) << 11) + t;
    const float* lwq = lw + 56 * q;

    double p = 0.0;
    #pragma unroll 8
    for (int i = 0; i < 56; ++i)
        p += (double)xb[(size_t)i << 11] * (double)lwq[i];
    sp[q][tl] = p;
    __syncthreads();

    if (threadIdx.x < 256) {
        const int tt = blockIdx.x * 256 + threadIdx.x;
        double acc = (sp[0][threadIdx.x] + sp[1][threadIdx.x])
                   + (sp[2][threadIdx.x] + sp[3][threadIdx.x]);

        double w = 5.2 + acc * 9.6;
        w = fmin(fmax(w, 0.4), 10.0);
        double iw2 = 1.0 / (w * w);

        // norm over linspace(-60,60,130): symmetric -> 2x half-sum,
        // terms G^{(2u+1)^2} via power recurrence (2 exps total)
        const double s = 120.0 / 129.0;
        double G  = exp(-0.125 * s * s * iw2);
        double G2 = G * G, G4 = G2 * G2, G8 = G4 * G4;
        double term = G, cmul = G8, norm = G;
        for (int u = 1; u <= 64; ++u) { term *= cmul; cmul *= G8; norm += term; }
        norm *= 2.0;

        double P = exp(-0.5 * iw2), P2 = P * P;
        double a = 1.0, bm = P, inv = 1.0 / norm;
        double* kr = kernG + (size_t)(b * TTT + tt) * 7;
        kr[0] = inv;                      // center tap
        #pragma unroll
        for (int d = 1; d <= 6; ++d) {
            a *= bm; bm *= P2;
            kr[d] = a * inv;              // tap at distance d (symmetric)
        }
    }
}

// ---------------------------------------------------------------------------
// kf v13: fused conv + LIF scan + spikes; DUAL-SEGMENT scan in ONE wave.
// grid (8,32) x 512 threads, 1 block/CU (LDS ~105KB).
// wave0 lanes 0..27  = segment A: scans tiles 0..9 exactly (true init).
// wave0 lanes 32..59 = segment B: warms tiles 5..9 from mem=0 (W=640 steps,
//   bit-exact per r10/r11 absmax=0.0), then outputs tiles 10..15.
// Both lane groups advance with every wave instruction -> 2 tile-scans per
// phase at the SAME per-step latency; serial wall drops 18 -> 12 phases.
// Conv (waves 1..7, v6 code) fills a 7-slot f32 Is ring; each tile conv'd
// ONCE (shared by A-output and B-warmup) -> FETCH unchanged vs r5.
// f32 Is rounding validated by r9 (f32 I + f32 scan: absmax 0.0); here the
// scan stays f64 (r5 idiom untouched; cvt f64<-f32 in off-chain prefetch).
// Schedule (phase p = 1..12): A reads slot (p-1)%7; B reads (p+4)%7; conv
// writes (p+5)%7 [gaps 6,1 mod 7 -> no collision; tile t lives write p=t-5
// .. last read p=t+1 < overwrite p=t+2]. Prologue: direct-conv tiles 0..5,
// prefetch 6,7. Out-writes: A tile k-2 @ phases 2..11; B tile k+3 @ 7..12.
// ---------------------------------------------------------------------------
__global__ __launch_bounds__(512) void kf(
    const float* __restrict__ x, const double* __restrict__ kernG,
    float* __restrict__ out)
{
    __shared__ float IsR[NSLOT][TPB][IROW];            // 103,936 B
    __shared__ unsigned long long bitsb[2][2][CG][2];  // [parity][seg][c][half]

    const int b   = blockIdx.y;
    const int cgi = blockIdx.x;
    const int c0  = cgi * CG;
    const int tid = threadIdx.x;
    const int ctid = tid - 64;          // 0..447 for conv waves

    const float*  xbase = x + (((size_t)(b * CCH)) << 11);
    const double* kbase = kernG + (size_t)(b * TTT) * 7;
    float* obase = out + (((size_t)(b * CCH + c0)) << 11);

    double mem = 0.0;   // scan state; exact init for A, warm-start guess for B
    bool   r   = false;

    const int tl = ctid & 63;           // conv lane t within half
    const int cw = ctid >> 6;           // conv wave group 0..6
    const int cb = CPW * cw;            // first channel (relative) of group

    // issue all global loads for one tile into a reg set (conv waves only)
    auto issue = [&](int tile, float (&rv)[2][16], double (&kv)[2][7]) {
        const int gt0 = tile * TPB;
        #pragma unroll
        for (int h = 0; h < 2; ++h) {
            const int tt = gt0 + tl + 64 * h;
            #pragma unroll
            for (int i = 0; i < 16; ++i) {
                int cr = c0 + cb - 6 + i;
                rv[h][i] = (cr >= 0 && cr < CCH)
                         ? xbase[((size_t)cr << 11) + tt] : 0.f;
            }
            const double* kp = kbase + (size_t)tt * 7;
            #pragma unroll
            for (int i = 0; i < 7; ++i) kv[h][i] = kp[i];
        }
    };

    // conv one tile from a reg set into ring slot (f64 conv, one f32 round)
    auto conv_store = [&](int slot, float (&rv)[2][16], double (&kv)[2][7]) {
        #pragma unroll
        for (int h = 0; h < 2; ++h) {
            double kk7[7];
            #pragma unroll
            for (int i = 0; i < 7; ++i) kk7[i] = kv[h][i];
            double xv[16];
            #pragma unroll
            for (int i = 0; i < 16; ++i) xv[i] = (double)rv[h][i];
            #pragma unroll
            for (int c = 0; c < CPW; ++c) {
                double acc = 0.0;
                #pragma unroll
                for (int kk = 0; kk < 13; ++kk) {
                    int d = kk < 6 ? 6 - kk : kk - 6;
                    acc = fma(xv[c + kk], kk7[d], acc);
                }
                double xvv = xv[c + 6];
                double dd  = xvv - acc;
                IsR[slot][tl + 64 * h][cb + c] =
                    (float)(xvv - (dd > 0.0 ? dd : 0.0));
            }
        }
    };

    // fire-and-forget spike store of one tile from a bitsb slot
    auto writeTile = [&](int t, int par, int seg) {
        const int t0o = t * TPB;
        const int c = ctid >> 4, q = ctid & 15;
        #pragma unroll
        for (int h = 0; h < 2; ++h) {
            unsigned long long bits = bitsb[par][seg][c][h] >> (4 * q);
            float4 v;
            v.x = (bits & 1ull) ? 1.0f : 0.0f;
            v.y = (bits & 2ull) ? 1.0f : 0.0f;
            v.z = (bits & 4ull) ? 1.0f : 0.0f;
            v.w = (bits & 8ull) ? 1.0f : 0.0f;
            *(float4*)(obase + ((size_t)c << 11) + t0o + 64 * h + 4 * q) = v;
        }
    };

    auto phase = [&](int k, float (&rv)[2][16], double (&kv)[2][7]) {
        if (tid >= 64) {
            if (k >= 2 && k <= 11) writeTile(k - 2, (k - 1) & 1, 0); // A out
            if (k >= 7)            writeTile(k + 3, (k - 1) & 1, 1); // B out
            if (k <= 10) conv_store((k + 5) % NSLOT, rv, kv);        // conv
            if (k <= 8)  issue(k + 7, rv, kv);                       // prefetch
        } else {
            // dual-segment scan: lanes 0..27 = A (tile k-1), 32..59 = B (k+4)
            const int seg = tid >> 5;
            const int c   = tid & 31;
            const int myt = seg ? (k + 4) : (k - 1);
            const bool act = (c < CG) && (seg ? (k <= 11) : (k <= 10));
            __builtin_amdgcn_s_setprio(1);
            if (act) {
                const float* isb = &IsR[myt % NSLOT][0][c];
                unsigned long long bits0 = 0ull, bits1 = 0ull;
                double va[8], vb8[8], ca[8], cb2[8];
                #pragma unroll
                for (int j2 = 0; j2 < 8; ++j2) va[j2] = (double)isb[j2 * IROW];
                #pragma unroll
                for (int j2 = 0; j2 < 8; ++j2) ca[j2] = va[j2] - 1.0;
                for (int g2 = 0; g2 < TPB; g2 += 16) {
                    #pragma unroll
                    for (int j2 = 0; j2 < 8; ++j2)
                        vb8[j2] = (double)isb[(g2 + 8 + j2) * IROW];
                    #pragma unroll
                    for (int j2 = 0; j2 < 8; ++j2) cb2[j2] = vb8[j2] - 1.0;
                    #pragma unroll
                    for (int j2 = 0; j2 < 8; ++j2) {
                        double m1 = fma(0.95, mem, va[j2]);
                        double m2 = fma(0.95, mem, ca[j2]);
                        mem = r ? m2 : m1;
                        r = mem > 1.0;
                        const int s = g2 + j2;
                        unsigned long long bbit =
                            (unsigned long long)(r ? 1 : 0) << (s & 63);
                        if (s < 64) bits0 |= bbit; else bits1 |= bbit;
                    }
                    if (g2 + 16 < TPB) {
                        #pragma unroll
                        for (int j2 = 0; j2 < 8; ++j2)
                            va[j2] = (double)isb[(g2 + 16 + j2) * IROW];
                        #pragma unroll
                        for (int j2 = 0; j2 < 8; ++j2) ca[j2] = va[j2] - 1.0;
                    }
                    #pragma unroll
                    for (int j2 = 0; j2 < 8; ++j2) {
                        double m1 = fma(0.95, mem, vb8[j2]);
                        double m2 = fma(0.95, mem, cb2[j2]);
                        mem = r ? m2 : m1;
                        r = mem > 1.0;
                        const int s = g2 + 8 + j2;
                        unsigned long long bbit =
                            (unsigned long long)(r ? 1 : 0) << (s & 63);
                        if (s < 64) bits0 |= bbit; else bits1 |= bbit;
                    }
                }
                bitsb[k & 1][seg][c][0] = bits0;
                bitsb[k & 1][seg][c][1] = bits1;
            }
            __builtin_amdgcn_s_setprio(0);
        }
        bar_lds();
    };

    // ping-pong register sets (statically indexed — rule #20)
    float  rA[2][16], rB[2][16];
    double kA[2][7],  kB[2][7];

    // ---- prologue: direct-conv tiles 0..5 into ring; prefetch tiles 6,7 ----
    if (tid >= 64) {
        for (int i = 0; i < 6; ++i) {
            issue(i, rA, kA);           // blocking via compiler data-dep waits
            conv_store(i, rA, kA);
        }
        issue(6, rB, kB);               // consumed phase 1 (odd -> rB)
        issue(7, rA, kA);               // consumed phase 2 (even -> rA)
    }
    bar_lds();

    // 12 phases, unrolled by 2 so reg-set parity is static (odd=rB, even=rA)
    for (int kk = 1; kk <= 12; kk += 2) {
        phase(kk,     rB, kB);
        phase(kk + 1, rA, kA);
    }
}

// ---------------------------------------------------------------------------
extern "C" void kernel_launch(void* const* d_in, const int* in_sizes, int n_in,
                              void* d_out, int out_size, void* d_ws, size_t ws_size,
                              hipStream_t stream)
{
    const float* x  = (const float*)d_in[0];   // (32,1,224,2048) f32
    const float* lw = (const float*)d_in[1];   // (1,224) f32
    float* out = (float*)d_out;                // (32,1,224,2048) f32

    double* kernG = (double*)d_ws;             // 65536 * 7 * 8 = 3,670,016 B

    kw<<<dim3(TTT / 256, BB), 1024, 0, stream>>>(x, lw, kernG);
    kf<<<dim3(NCG, BB), 512, 0, stream>>>(x, kernG, out);
}